// Round 5
// baseline (73.141 us; speedup 1.0000x reference)
//
#include <hip/hip_runtime.h>

#define N_VIEWS 5
#define N_JOINTS 15
#define HM_H 128
#define HM_W 240
#define PB 4
#define VXn 64
#define VYn 64
#define VZn 64
#define FXn 253
#define FYn 253
#define FZn 64
#define JP 16   // joints padded to 16

typedef float        vf2 __attribute__((ext_vector_type(2)));
typedef unsigned int vu4 __attribute__((ext_vector_type(4)));

// ---------------------------------------------------------------------------
// Kernel 1: transpose+quantize heatmaps (V,J,H,W) f32 -> (V,H,W,16) u8.
// ---------------------------------------------------------------------------
__global__ void transpose_hm_kernel(const float* __restrict__ hm,
                                    unsigned char* __restrict__ T) {
    int t = blockIdx.x * blockDim.x + threadIdx.x;  // over V*H*W
    const int total = N_VIEWS * HM_H * HM_W;
    if (t >= total) return;
    int x = t % HM_W;
    int vy = t / HM_W;
    int y = vy % HM_H;
    int v = vy / HM_H;
    unsigned int w[4] = {0u, 0u, 0u, 0u};
#pragma unroll
    for (int j = 0; j < N_JOINTS; ++j) {
        float val = hm[(((size_t)v * N_JOINTS + j) * HM_H + y) * HM_W + x];
        float q = rintf(val * 255.0f);
        q = fminf(fmaxf(q, 0.0f), 255.0f);
        w[j >> 2] |= ((unsigned int)q) << ((j & 3) * 8);
    }
    vu4* dst = (vu4*)(T + (size_t)t * JP);
    vu4 o; o.x = w[0]; o.y = w[1]; o.z = w[2]; o.w = w[3];
    *dst = o;
}

// ---------------------------------------------------------------------------
// Kernel 2: pack 2x2 bilinear footprint into one 64B record per (v,y,x).
// T2[v][y][x] = { T1[y][x], T1[y][x+1], T1[y+1][x], T1[y+1][x+1] } (clamped).
// One record = one cacheline = all 4 taps of one view.
// ---------------------------------------------------------------------------
__global__ void pack2x2_kernel(const unsigned char* __restrict__ T1,
                               unsigned char* __restrict__ T2) {
    int t = blockIdx.x * blockDim.x + threadIdx.x;  // over V*H*W
    const int total = N_VIEWS * HM_H * HM_W;
    if (t >= total) return;
    int x = t % HM_W;
    int vy = t / HM_W;
    int y = vy % HM_H;
    int v = vy / HM_H;
    int x1 = min(x + 1, HM_W - 1);
    int y1 = min(y + 1, HM_H - 1);
    const vu4* base = (const vu4*)T1;
    vu4 r00 = base[((size_t)v * HM_H + y) * HM_W + x];
    vu4 r01 = base[((size_t)v * HM_H + y) * HM_W + x1];
    vu4 r10 = base[((size_t)v * HM_H + y1) * HM_W + x];
    vu4 r11 = base[((size_t)v * HM_H + y1) * HM_W + x1];
    vu4* dst = (vu4*)(T2 + (size_t)t * 64);
    dst[0] = r00; dst[1] = r01; dst[2] = r10; dst[3] = r11;
}

// ---------------------------------------------------------------------------
// Kernel 3: main projection. One thread per voxel (p, ix, iy, iz).
// block = (64,4): lane = iz. grid = (16, 64, 4).
// Per view: ONE 64B record (4x dwordx4, same line). Degenerate-tap handling
// folded into entry weights, computed off the load critical path.
// ---------------------------------------------------------------------------
__global__ __launch_bounds__(256) void project_kernel(
    const unsigned char* __restrict__ T2,  // (V,H,W) 64B records
    const float* __restrict__ sg,          // (V,FX,FY,FZ,2)
    const float* __restrict__ pc,          // (P,7)
    float* __restrict__ out)               // (P,J,VX,VY,VZ)
{
    const int iz = threadIdx.x;                       // 0..63
    const int iy = blockIdx.x * 4 + threadIdx.y;      // 0..63
    const int ix = blockIdx.y;                        // 0..63
    const int p  = blockIdx.z;                        // 0..3

    // ---- per-proposal scalars (wave-uniform) ----
    const float pw = pc[p * 7 + 5];
    const float ph = pc[p * 7 + 6];
    int mask_x = max((int)((1.0f - pw) / 2.0f * (float)(VXn - 1)), 0);
    int mask_y = max((int)((1.0f - ph) / 2.0f * (float)(VYn - 1)), 0);

    float tx = pc[p * 7 + 0] + 4000.0f; tx = tx - 0.0f;      tx = tx - 1000.0f;
    float ty = pc[p * 7 + 1] + 4000.0f; ty = ty - (-500.0f); ty = ty - 1000.0f;
    float tz = pc[p * 7 + 2] + 1000.0f; tz = tz - 800.0f;    tz = tz - 1000.0f;
    tx = tx / 8000.0f * 252.0f;
    ty = ty / 8000.0f * 252.0f;
    tz = tz / 2000.0f * 63.0f;
    int cx = (int)rintf(tx);
    int cy = (int)rintf(ty);
    int cz = (int)rintf(tz);

    int x_start = max(-cx, 0) + mask_x;
    int x_end   = min(FXn - cx, VXn) - mask_x;
    int y_start = max(-cy, 0) + mask_y;
    int y_end   = min(FYn - cy, VYn) - mask_y;
    int z_start = max(-cz, 0);
    int z_end   = min(FZn - cz, VZn);

    const bool valid = (ix >= x_start && ix < x_end) &&
                       (iy >= y_start && iy < y_end) &&
                       (iz >= z_start && iz < z_end);

    const size_t out_base = ((((size_t)p * N_JOINTS) * VXn + ix) * VYn + iy) * VZn + iz;
    const size_t out_jstride = (size_t)VXn * VYn * VZn;

    // Wave-level early-out: x,y validity is uniform across the wave (lane=iz).
    unsigned long long mv = __ballot(valid ? 1 : 0);
    if (mv == 0ull) {
#pragma unroll
        for (int j = 0; j < N_JOINTS; ++j)
            __builtin_nontemporal_store(0.0f, &out[out_base + j * out_jstride]);
        return;
    }

    const int fx = min(max(cx + ix, 0), FXn - 1);
    const int fy = min(max(cy + iy, 0), FYn - 1);
    const int fz = min(max(cz + iz, 0), FZn - 1);

    const size_t sg_base = (((size_t)fx * FYn + fy) * FZn + fz) * 2;
    const size_t sg_vstride = (size_t)FXn * FYn * FZn * 2;

    // ---- stage 1: load all sample coords (coalesced, non-temporal) ----
    vf2 g[N_VIEWS];
#pragma unroll
    for (int v = 0; v < N_VIEWS; ++v)
        g[v] = __builtin_nontemporal_load(
            (const vf2*)(sg + sg_base + (size_t)v * sg_vstride));

    // ---- stage 2: record offsets + folded entry weights per view ----
    float W00[N_VIEWS], W01[N_VIEWS], W10[N_VIEWS], W11[N_VIEWS];
    unsigned off[N_VIEWS];
#pragma unroll
    for (int v = 0; v < N_VIEWS; ++v) {
        float px = (g[v].x + 1.0f) * 0.5f * (float)(HM_W - 1);
        float py = (g[v].y + 1.0f) * 0.5f * (float)(HM_H - 1);
        float x0f = floorf(px), y0f = floorf(py);
        float wx1 = px - x0f,  wy1 = py - y0f;
        float wx0 = 1.0f - wx1, wy0 = 1.0f - wy1;
        float x1f = x0f + 1.0f, y1f = y0f + 1.0f;
        float okx0 = (x0f >= 0.0f && x0f < (float)HM_W) ? 1.0f : 0.0f;
        float okx1 = (x1f >= 0.0f && x1f < (float)HM_W) ? 1.0f : 0.0f;
        float oky0 = (y0f >= 0.0f && y0f < (float)HM_H) ? 1.0f : 0.0f;
        float oky1 = (y1f >= 0.0f && y1f < (float)HM_H) ? 1.0f : 0.0f;
        int x0i = (int)x0f, y0i = (int)y0f;
        int rx = min(max(x0i, 0), HM_W - 1);
        int ry = min(max(y0i, 0), HM_H - 1);
        int ex = min(max(x0i + 1, 0), HM_W - 1) - rx;   // 0 or 1
        int ey = min(max(y0i + 1, 0), HM_H - 1) - ry;   // 0 or 1
        float w00 = wx0 * wy0 * okx0 * oky0;
        float w10 = wx1 * wy0 * okx1 * oky0;
        float w01 = wx0 * wy1 * okx0 * oky1;
        float w11 = wx1 * wy1 * okx1 * oky1;
        float fex = (float)ex, fey = (float)ey;
        float gex = 1.0f - fex, gey = 1.0f - fey;
        // fold degenerate taps (clamped duplicates) onto the entries they hit
        W00[v] = w00 + gex * w10 + gey * w01 + gex * gey * w11;
        W01[v] = fex * (w10 + gey * w11);
        W10[v] = fey * (w01 + gex * w11);
        W11[v] = fex * fey * w11;
        off[v] = ((unsigned)(v * HM_H + ry) * HM_W + (unsigned)rx) * 64u;
    }

    float acc[N_JOINTS];
#pragma unroll
    for (int j = 0; j < N_JOINTS; ++j) acc[j] = 0.0f;

    // ---- stage 3: batched record loads (one cacheline per view) ----
#pragma unroll
    for (int b = 0; b < 2; ++b) {
        const int vbeg = (b == 0) ? 0 : 3;
        const int vend = (b == 0) ? 3 : N_VIEWS;
        vu4 rec[3][4];
#pragma unroll
        for (int v = vbeg; v < vend; ++v) {
            const vu4* r = (const vu4*)(T2 + off[v]);
            rec[v - vbeg][0] = r[0];
            rec[v - vbeg][1] = r[1];
            rec[v - vbeg][2] = r[2];
            rec[v - vbeg][3] = r[3];
        }
#pragma unroll
        for (int v = vbeg; v < vend; ++v) {
            const unsigned int* a = (const unsigned int*)&rec[v - vbeg][0];
            const unsigned int* bb = (const unsigned int*)&rec[v - vbeg][1];
            const unsigned int* c = (const unsigned int*)&rec[v - vbeg][2];
            const unsigned int* d = (const unsigned int*)&rec[v - vbeg][3];
#pragma unroll
            for (int j = 0; j < N_JOINTS; ++j) {
                int word = j >> 2, sh = (j & 3) * 8;
                float fa = (float)((a[word] >> sh) & 0xffu);
                float fb = (float)((bb[word] >> sh) & 0xffu);
                float fc = (float)((c[word] >> sh) & 0xffu);
                float fd = (float)((d[word] >> sh) & 0xffu);
                acc[j] += W00[v] * fa + W01[v] * fb + W10[v] * fc + W11[v] * fd;
            }
        }
    }

    const float scale = valid ? (0.2f / 255.0f) : 0.0f;
#pragma unroll
    for (int j = 0; j < N_JOINTS; ++j) {
        float vlu = acc[j] * scale;
        vlu = fminf(fmaxf(vlu, 0.0f), 1.0f);
        __builtin_nontemporal_store(vlu, &out[out_base + j * out_jstride]);
    }
}

// ---------------------------------------------------------------------------
// Kernel 4: the constant grids output (3, 4096, 2).
// ---------------------------------------------------------------------------
__global__ void grids_kernel(float* __restrict__ out) {
    int t = blockIdx.x * blockDim.x + threadIdx.x;
    if (t >= 3 * 4096) return;
    int g = t / 4096;
    int idx = t % 4096;
    int a = idx / 64;
    int b = idx % 64;
    const float step = 2000.0f / 63.0f;
    float va = -1000.0f + (float)a * step;
    float vb = -1000.0f + (float)b * step;
    float o0, o1;
    if (g == 0)      { o0 = va + 0.0f;      o1 = vb + (-500.0f); }
    else if (g == 1) { o0 = va + 0.0f;      o1 = vb + 800.0f;    }
    else             { o0 = va + (-500.0f); o1 = vb + 800.0f;    }
    out[(size_t)t * 2 + 0] = o0;
    out[(size_t)t * 2 + 1] = o1;
}

extern "C" void kernel_launch(void* const* d_in, const int* in_sizes, int n_in,
                              void* d_out, int out_size, void* d_ws, size_t ws_size,
                              hipStream_t stream) {
    const float* hm = (const float*)d_in[0];   // (5,15,128,240)
    const float* sg = (const float*)d_in[1];   // (5,253,253,64,2)
    const float* pc = (const float*)d_in[2];   // (4,7)
    float* out = (float*)d_out;

    const int total = N_VIEWS * HM_H * HM_W;                  // 153600
    unsigned char* T1 = (unsigned char*)d_ws;                 // 2.46 MB
    unsigned char* T2 = T1 + (size_t)total * JP;              // 9.83 MB

    transpose_hm_kernel<<<(total + 255) / 256, 256, 0, stream>>>(hm, T1);
    pack2x2_kernel<<<(total + 255) / 256, 256, 0, stream>>>(T1, T2);

    dim3 blk(64, 4, 1);
    dim3 grd(16, 64, 4);  // (iy/4, ix, p)
    project_kernel<<<grd, blk, 0, stream>>>(T2, sg, pc, out);

    const size_t grids_off = (size_t)PB * N_JOINTS * VXn * VYn * VZn;
    grids_kernel<<<(3 * 4096 + 255) / 256, 256, 0, stream>>>(out + grids_off);
}